// Round 1
// baseline (908.686 us; speedup 1.0000x reference)
//
#include <hip/hip_runtime.h>
#include <hip/hip_bf16.h>
#include <cstdint>

// Problem constants (setup_inputs: B=2, T=4096, D=1024, F=4096, S=4096)
#define BB   2
#define TT   4096
#define DD   1024
#define FF   4096
#define SS   4096
#define MTOK (BB * TT)   // 8192 tokens
#define NCHUNK 32
#define TCHUNK 128

typedef __bf16 bf16x8 __attribute__((ext_vector_type(8)));
typedef float  f32x4  __attribute__((ext_vector_type(4)));
typedef __attribute__((address_space(3))) char lds_char;
typedef __attribute__((address_space(1))) char g_char;

// ---------------------------------------------------------------------------
// fp32 -> bf16 convert (weights)
// ---------------------------------------------------------------------------
__global__ __launch_bounds__(256) void cvt_kernel(const float* __restrict__ s,
                                                  __hip_bfloat16* __restrict__ d,
                                                  int n4) {
  int i = blockIdx.x * 256 + threadIdx.x;
  if (i < n4) {
    float4 v = ((const float4*)s)[i];
    union { ushort4 u; __hip_bfloat16 h[4]; } p;
    p.h[0] = __float2bfloat16(v.x);
    p.h[1] = __float2bfloat16(v.y);
    p.h[2] = __float2bfloat16(v.z);
    p.h[3] = __float2bfloat16(v.w);
    ((ushort4*)d)[i] = p.u;
  }
}

// ---------------------------------------------------------------------------
// combine the 3 causal depthwise kernels into one 15-tap (padded to 16) table
// wcomb[d][j] multiplies x[t-j]; jax conv is cross-correlation so tap j uses
// w_k[d, 0, k-1-j].
// ---------------------------------------------------------------------------
__global__ void wcomb_kernel(const float* __restrict__ w3, const float* __restrict__ w7,
                             const float* __restrict__ w15, float* __restrict__ wc) {
  int d = blockIdx.x * 256 + threadIdx.x;
  if (d >= DD) return;
  for (int j = 0; j < 16; j++) {
    float v = 0.f;
    if (j < 15) {
      v = w15[d * 15 + (14 - j)];
      if (j < 7) v += w7[d * 7 + (6 - j)];
      if (j < 3) v += w3[d * 3 + (2 - j)];
    }
    wc[d * 16 + j] = v;
  }
}

// ---------------------------------------------------------------------------
// RMSNorm: one block per row of 1024, fp32 in, fp32 or bf16 out
// ---------------------------------------------------------------------------
template <int OUT_BF16>
__global__ __launch_bounds__(256) void rms_kernel(const float* __restrict__ x,
                                                  const float* __restrict__ w,
                                                  float* __restrict__ of,
                                                  __hip_bfloat16* __restrict__ ob) {
  const int row = blockIdx.x;
  const int tid = threadIdx.x;
  float4 v = ((const float4*)(x + (size_t)row * DD))[tid];
  float ss = v.x * v.x + v.y * v.y + v.z * v.z + v.w * v.w;
  for (int off = 32; off > 0; off >>= 1) ss += __shfl_down(ss, off, 64);
  __shared__ float wsum[4];
  if ((tid & 63) == 0) wsum[tid >> 6] = ss;
  __syncthreads();
  float tot = wsum[0] + wsum[1] + wsum[2] + wsum[3];
  float rinv = 1.0f / sqrtf(tot * (1.0f / DD) + 1e-6f);
  float4 wg = ((const float4*)w)[tid];
  float4 o;
  o.x = v.x * wg.x * rinv; o.y = v.y * wg.y * rinv;
  o.z = v.z * wg.z * rinv; o.w = v.w * wg.w * rinv;
  if (OUT_BF16) {
    union { ushort4 u; __hip_bfloat16 h[4]; } p;
    p.h[0] = __float2bfloat16(o.x); p.h[1] = __float2bfloat16(o.y);
    p.h[2] = __float2bfloat16(o.z); p.h[3] = __float2bfloat16(o.w);
    ((ushort4*)ob)[(size_t)row * 256 + tid] = p.u;
  } else {
    ((float4*)of)[(size_t)row * 256 + tid] = o;
  }
}

// ---------------------------------------------------------------------------
// multi-scale causal depthwise conv, 15 taps combined, LDS tiled with halo
// grid: (T/64, D/64, B), block 256
// ---------------------------------------------------------------------------
__global__ __launch_bounds__(256) void conv_kernel(const float* __restrict__ xn,
                                                   const float* __restrict__ wc,
                                                   __hip_bfloat16* __restrict__ outp) {
  __shared__ float xt[78][64];
  __shared__ float wt[64][15];
  const int b = blockIdx.z, t0 = blockIdx.x * 64, d0 = blockIdx.y * 64;
  const int tid = threadIdx.x;
  const int dl = tid & 63;
  for (int idx = tid; idx < 64 * 15; idx += 256) {
    int d = idx / 15, j = idx % 15;
    wt[d][j] = wc[(d0 + d) * 16 + j];
  }
  for (int r = tid >> 6; r < 78; r += 4) {
    int t = t0 - 14 + r;
    xt[r][dl] = (t >= 0) ? xn[((size_t)b * TT + t) * DD + d0 + dl] : 0.f;
  }
  __syncthreads();
  for (int tl = tid >> 6; tl < 64; tl += 4) {
    float acc = 0.f;
#pragma unroll
    for (int j = 0; j < 15; j++) acc += wt[dl][j] * xt[tl + 14 - j][dl];
    outp[((size_t)b * TT + t0 + tl) * DD + d0 + dl] = __float2bfloat16(acc);
  }
}

// ---------------------------------------------------------------------------
// bf16 GEMM, C[M,N] = A[M,K] @ B[N,K]^T, m97 structure:
// 128x128 tile, BK=32, global_load_lds width 16, 4 waves x (4x4 of 16x16 mfma)
// Epilogues:
//  0: outf[idx] = resid[idx] + acc          (residual add)
//  1: z/htilde: bias + sigmoid on cols<1024 (N=2048)
//  2: outb = bf16(acc)
//  3: outf = acc (fp32 scores)
//  4: outb = bf16(silu(acc))
//  5: outb = bf16(acc * mulin[idx])
// ---------------------------------------------------------------------------
template <int EPI>
__global__ __launch_bounds__(256, 2) void gemm_bt(
    const __hip_bfloat16* __restrict__ A, const __hip_bfloat16* __restrict__ Bm,
    const int M, const int N, const int K,
    const float* __restrict__ resid, float* __restrict__ outf,
    __hip_bfloat16* __restrict__ outb,
    const float* __restrict__ bias0, const float* __restrict__ bias1,
    const __hip_bfloat16* __restrict__ mulin) {
  __shared__ __align__(16) __hip_bfloat16 As[128 * 32];
  __shared__ __align__(16) __hip_bfloat16 Bs[128 * 32];
  const int tid = threadIdx.x;
  const int lane = tid & 63;
  const int wave = tid >> 6;
  const int fm = lane & 15, fq = lane >> 4;
  const int tileN = blockIdx.x * 128;
  const int tileM = blockIdx.y * 128;
  const int wm = (wave & 1) * 64, wn = (wave >> 1) * 64;

  f32x4 acc[4][4] = {};

  const int srow = tid >> 2;          // 0..63
  const int scol = (tid & 3) * 8;     // bf16 element offset within BK
  const __hip_bfloat16* gA = A + (size_t)(tileM + srow) * K + scol;
  const __hip_bfloat16* gB = Bm + (size_t)(tileN + srow) * K + scol;
  lds_char* ldsA = (lds_char*)(&As[0]);
  lds_char* ldsB = (lds_char*)(&Bs[0]);
  const int wbyte = wave * 1024;      // lane*16 is implicit in global_load_lds

  for (int k0 = 0; k0 < K; k0 += 32) {
    __syncthreads();
    __builtin_amdgcn_global_load_lds((g_char*)(void*)(gA + k0),                  ldsA + wbyte,        16, 0, 0);
    __builtin_amdgcn_global_load_lds((g_char*)(void*)(gA + k0 + (size_t)64 * K), ldsA + wbyte + 4096, 16, 0, 0);
    __builtin_amdgcn_global_load_lds((g_char*)(void*)(gB + k0),                  ldsB + wbyte,        16, 0, 0);
    __builtin_amdgcn_global_load_lds((g_char*)(void*)(gB + k0 + (size_t)64 * K), ldsB + wbyte + 4096, 16, 0, 0);
    __syncthreads();
    bf16x8 af[4], bfr[4];
#pragma unroll
    for (int i = 0; i < 4; i++) {
      af[i]  = *(const bf16x8*)(As + (wm + i * 16 + fm) * 32 + fq * 8);
      bfr[i] = *(const bf16x8*)(Bs + (wn + i * 16 + fm) * 32 + fq * 8);
    }
#pragma unroll
    for (int i = 0; i < 4; i++)
#pragma unroll
      for (int j = 0; j < 4; j++)
        acc[i][j] = __builtin_amdgcn_mfma_f32_16x16x32_bf16(af[i], bfr[j], acc[i][j], 0, 0, 0);
  }

  // epilogue: C/D layout col = lane&15, row = (lane>>4)*4 + reg  [m89/m91]
#pragma unroll
  for (int i = 0; i < 4; i++) {
#pragma unroll
    for (int j = 0; j < 4; j++) {
      const int c = tileN + wn + j * 16 + fm;
#pragma unroll
      for (int r = 0; r < 4; r++) {
        const int rw = tileM + wm + i * 16 + fq * 4 + r;
        const size_t idx = (size_t)rw * N + c;
        float v = acc[i][j][r];
        if constexpr (EPI == 0) {
          outf[idx] = resid[idx] + v;
        } else if constexpr (EPI == 1) {
          v += (c < DD) ? bias0[c] : bias1[c - DD];
          if (c < DD) v = 1.f / (1.f + __expf(-v));
          outf[idx] = v;
        } else if constexpr (EPI == 2) {
          outb[idx] = __float2bfloat16(v);
        } else if constexpr (EPI == 3) {
          outf[idx] = v;
        } else if constexpr (EPI == 4) {
          outb[idx] = __float2bfloat16(v / (1.f + __expf(-v)));
        } else {
          outb[idx] = __float2bfloat16(v * __bfloat162float(mulin[idx]));
        }
      }
    }
  }
}

// ---------------------------------------------------------------------------
// MinGRU chunked parallel scan over zht [MTOK, 2048] (z | htilde)
// pass1: per-chunk affine coeffs (A,B); pass2: scan chunks; pass3: replay+add
// ---------------------------------------------------------------------------
__global__ __launch_bounds__(256) void scan_pass1(const float* __restrict__ zht,
                                                  float* __restrict__ cA,
                                                  float* __restrict__ cB) {
  const int b = blockIdx.z, c = blockIdx.y;
  const int d = blockIdx.x * 256 + threadIdx.x;
  const float* base = zht + (size_t)b * TT * 2048;
  float A = 1.f, Bc = 0.f;
  const int t0 = c * TCHUNK;
  for (int t = t0; t < t0 + TCHUNK; t++) {
    const float* rowp = base + (size_t)t * 2048;
    float z = rowp[d];
    float h = rowp[DD + d];
    float om = 1.f - z;
    A *= om;
    Bc = om * Bc + z * h;
  }
  size_t idx = ((size_t)b * NCHUNK + c) * DD + d;
  cA[idx] = A;
  cB[idx] = Bc;
}

__global__ __launch_bounds__(256) void scan_pass2(const float* __restrict__ hp,
                                                  const float* __restrict__ cA,
                                                  const float* __restrict__ cB,
                                                  float* __restrict__ hstart,
                                                  float* __restrict__ hlast) {
  const int b = blockIdx.y;
  const int d = blockIdx.x * 256 + threadIdx.x;
  float h = hp[b * DD + d];
  for (int c = 0; c < NCHUNK; c++) {
    size_t idx = ((size_t)b * NCHUNK + c) * DD + d;
    hstart[idx] = h;
    h = cA[idx] * h + cB[idx];
  }
  hlast[b * DD + d] = h;
}

__global__ __launch_bounds__(256) void scan_pass3(const float* __restrict__ zht,
                                                  const float* __restrict__ hstart,
                                                  float* __restrict__ x) {
  const int b = blockIdx.z, c = blockIdx.y;
  const int d = blockIdx.x * 256 + threadIdx.x;
  const float* base = zht + (size_t)b * TT * 2048;
  float h = hstart[((size_t)b * NCHUNK + c) * DD + d];
  const int t0 = c * TCHUNK;
  for (int t = t0; t < t0 + TCHUNK; t++) {
    const float* rowp = base + (size_t)t * 2048;
    float z = rowp[d];
    float ht = rowp[DD + d];
    h = (1.f - z) * h + z * ht;
    x[((size_t)b * TT + t) * DD + d] += h;
  }
}

// ---------------------------------------------------------------------------
// top-2 over S=4096 scores per row + softmax + gather slot_values -> bf16
// one block per row
// ---------------------------------------------------------------------------
__global__ __launch_bounds__(256) void topk_kernel(const float* __restrict__ scores,
                                                   const float* __restrict__ sv,
                                                   __hip_bfloat16* __restrict__ ret) {
  const int row = blockIdx.x;
  const int tid = threadIdx.x;
  const float* sr = scores + (size_t)row * SS;
  float v0 = -3.4e38f, v1 = -3.4e38f;
  int i0 = 0x7fffffff, i1 = 0x7fffffff;
  for (int j = tid; j < SS; j += 256) {
    float v = sr[j];
    if (v > v0) { v1 = v0; i1 = i0; v0 = v; i0 = j; }
    else if (v > v1) { v1 = v; i1 = j; }
  }
#define TKMERGE(w0, j0, w1, j1)                                              \
  {                                                                          \
    if (w0 > v0 || (w0 == v0 && j0 < i0)) {                                  \
      float t0v = v0; int t0i = i0; v0 = w0; i0 = j0;                        \
      if (t0v > w1 || (t0v == w1 && t0i < j1)) { v1 = t0v; i1 = t0i; }       \
      else { v1 = w1; i1 = j1; }                                             \
    } else {                                                                 \
      if (w0 > v1 || (w0 == v1 && j0 < i1)) { v1 = w0; i1 = j0; }            \
    }                                                                        \
  }
  for (int off = 32; off > 0; off >>= 1) {
    float w0 = __shfl_down(v0, off, 64), w1 = __shfl_down(v1, off, 64);
    int   j0 = __shfl_down(i0, off, 64), j1 = __shfl_down(i1, off, 64);
    TKMERGE(w0, j0, w1, j1);
  }
  __shared__ float wv0[4], wv1[4];
  __shared__ int   wi0[4], wi1[4];
  __shared__ float sattn[2];
  __shared__ int   sidx[2];
  if ((tid & 63) == 0) { int w = tid >> 6; wv0[w] = v0; wv1[w] = v1; wi0[w] = i0; wi1[w] = i1; }
  __syncthreads();
  if (tid == 0) {
    v0 = wv0[0]; i0 = wi0[0]; v1 = wv1[0]; i1 = wi1[0];
    for (int w = 1; w < 4; w++) { TKMERGE(wv0[w], wi0[w], wv1[w], wi1[w]); }
    float s0 = v0 * (1.f / 32.f), s1 = v1 * (1.f / 32.f);  // /sqrt(D)
    float e = __expf(s1 - s0);
    float denom = 1.f + e;
    sattn[0] = 1.f / denom;
    sattn[1] = e / denom;
    sidx[0] = i0; sidx[1] = i1;
  }
  __syncthreads();
  float a0 = sattn[0], a1 = sattn[1];
  const float4* r0 = (const float4*)(sv + (size_t)sidx[0] * DD);
  const float4* r1 = (const float4*)(sv + (size_t)sidx[1] * DD);
  float4 u = r0[tid], w4 = r1[tid];
  union { ushort4 u; __hip_bfloat16 h[4]; } p;
  p.h[0] = __float2bfloat16(a0 * u.x + a1 * w4.x);
  p.h[1] = __float2bfloat16(a0 * u.y + a1 * w4.y);
  p.h[2] = __float2bfloat16(a0 * u.z + a1 * w4.z);
  p.h[3] = __float2bfloat16(a0 * u.w + a1 * w4.w);
  ((ushort4*)(ret + (size_t)row * DD))[tid] = p.u;
#undef TKMERGE
}

// ---------------------------------------------------------------------------
extern "C" void kernel_launch(void* const* d_in, const int* in_sizes, int n_in,
                              void* d_out, int out_size, void* d_ws, size_t ws_size,
                              hipStream_t stream) {
  (void)in_sizes; (void)n_in; (void)out_size; (void)ws_size;
  const float* x_in   = (const float*)d_in[0];
  const float* h_prev = (const float*)d_in[1];
  const float* n1w    = (const float*)d_in[2];
  const float* w3     = (const float*)d_in[3];
  const float* w7     = (const float*)d_in[4];
  const float* w15    = (const float*)d_in[5];
  const float* mixw   = (const float*)d_in[6];
  const float* n2w    = (const float*)d_in[7];
  const float* wzw    = (const float*)d_in[8];
  const float* wzb    = (const float*)d_in[9];
  const float* whw    = (const float*)d_in[10];
  const float* whb    = (const float*)d_in[11];
  const float* n3w    = (const float*)d_in[12];
  const float* slotk  = (const float*)d_in[13];
  const float* slotv  = (const float*)d_in[14];
  const float* pqw    = (const float*)d_in[15];
  const float* pow_   = (const float*)d_in[16];
  const float* n4w    = (const float*)d_in[17];
  const float* gatew  = (const float*)d_in[18];
  const float* upw    = (const float*)d_in[19];
  const float* downw  = (const float*)d_in[20];
  float* out = (float*)d_out;

  char* ws = (char*)d_ws;
  size_t o = 0;
  auto alloc = [&](size_t bytes) {
    size_t r = o;
    o += (bytes + 255) & ~(size_t)255;
    return r;
  };
  __hip_bfloat16* wmix = (__hip_bfloat16*)(ws + alloc((size_t)DD * DD * 2));
  __hip_bfloat16* wzht = (__hip_bfloat16*)(ws + alloc((size_t)2 * DD * DD * 2));
  __hip_bfloat16* wpq  = (__hip_bfloat16*)(ws + alloc((size_t)DD * DD * 2));
  __hip_bfloat16* wsk  = (__hip_bfloat16*)(ws + alloc((size_t)SS * DD * 2));
  __hip_bfloat16* wpo  = (__hip_bfloat16*)(ws + alloc((size_t)DD * DD * 2));
  __hip_bfloat16* wg   = (__hip_bfloat16*)(ws + alloc((size_t)FF * DD * 2));
  __hip_bfloat16* wu   = (__hip_bfloat16*)(ws + alloc((size_t)FF * DD * 2));
  __hip_bfloat16* wd   = (__hip_bfloat16*)(ws + alloc((size_t)DD * FF * 2));
  float* wcomb = (float*)(ws + alloc((size_t)DD * 16 * 4));
  float* xws   = (float*)(ws + alloc((size_t)MTOK * DD * 4));
  __hip_bfloat16* xnb  = (__hip_bfloat16*)(ws + alloc((size_t)MTOK * DD * 2));
  __hip_bfloat16* qb   = (__hip_bfloat16*)(ws + alloc((size_t)MTOK * DD * 2));
  __hip_bfloat16* retr = (__hip_bfloat16*)(ws + alloc((size_t)MTOK * DD * 2));
  float* scanA  = (float*)(ws + alloc((size_t)BB * NCHUNK * DD * 4));
  float* scanB  = (float*)(ws + alloc((size_t)BB * NCHUNK * DD * 4));
  float* hstart = (float*)(ws + alloc((size_t)BB * NCHUNK * DD * 4));
  char* big = ws + alloc((size_t)MTOK * FF * 4);  // 134 MB shared region
  // aliases (lifetimes disjoint):
  float* xn1f           = (float*)big;                                   // phase 1
  __hip_bfloat16* convb = (__hip_bfloat16*)(big + (size_t)MTOK * DD * 4);// phase 1
  float* zht            = (float*)big;                                   // phase 2
  float* scores         = (float*)big;                                   // phase 3
  __hip_bfloat16* sg    = (__hip_bfloat16*)big;                          // phase 4
  __hip_bfloat16* ffin  = (__hip_bfloat16*)(big + (size_t)MTOK * FF * 2);// phase 4

  // weight conversions
  auto cvt = [&](const float* s, __hip_bfloat16* dp, int n) {
    cvt_kernel<<<n / 1024, 256, 0, stream>>>(s, dp, n / 4);
  };
  cvt(mixw, wmix, DD * DD);
  cvt(wzw, wzht, DD * DD);
  cvt(whw, wzht + (size_t)DD * DD, DD * DD);
  cvt(pqw, wpq, DD * DD);
  cvt(slotk, wsk, SS * DD);
  cvt(pow_, wpo, DD * DD);
  cvt(gatew, wg, FF * DD);
  cvt(upw, wu, FF * DD);
  cvt(downw, wd, DD * FF);
  wcomb_kernel<<<DD / 256, 256, 0, stream>>>(w3, w7, w15, wcomb);

  // 1. conv block
  rms_kernel<0><<<MTOK, 256, 0, stream>>>(x_in, n1w, xn1f, nullptr);
  conv_kernel<<<dim3(TT / 64, DD / 64, BB), 256, 0, stream>>>(xn1f, wcomb, convb);
  gemm_bt<0><<<dim3(DD / 128, MTOK / 128), 256, 0, stream>>>(
      convb, wmix, MTOK, DD, DD, x_in, xws, nullptr, nullptr, nullptr, nullptr);

  // 2. MinGRU
  rms_kernel<1><<<MTOK, 256, 0, stream>>>(xws, n2w, nullptr, xnb);
  gemm_bt<1><<<dim3(2048 / 128, MTOK / 128), 256, 0, stream>>>(
      xnb, wzht, MTOK, 2048, DD, nullptr, zht, nullptr, wzb, whb, nullptr);
  scan_pass1<<<dim3(DD / 256, NCHUNK, BB), 256, 0, stream>>>(zht, scanA, scanB);
  scan_pass2<<<dim3(DD / 256, BB), 256, 0, stream>>>(h_prev, scanA, scanB, hstart,
                                                     out + (size_t)MTOK * DD);
  scan_pass3<<<dim3(DD / 256, NCHUNK, BB), 256, 0, stream>>>(zht, hstart, xws);

  // 3. slot memory
  rms_kernel<1><<<MTOK, 256, 0, stream>>>(xws, n3w, nullptr, xnb);
  gemm_bt<2><<<dim3(DD / 128, MTOK / 128), 256, 0, stream>>>(
      xnb, wpq, MTOK, DD, DD, nullptr, nullptr, qb, nullptr, nullptr, nullptr);
  gemm_bt<3><<<dim3(SS / 128, MTOK / 128), 256, 0, stream>>>(
      qb, wsk, MTOK, SS, DD, nullptr, scores, nullptr, nullptr, nullptr, nullptr);
  topk_kernel<<<MTOK, 256, 0, stream>>>(scores, slotv, retr);
  gemm_bt<0><<<dim3(DD / 128, MTOK / 128), 256, 0, stream>>>(
      retr, wpo, MTOK, DD, DD, xws, xws, nullptr, nullptr, nullptr, nullptr);

  // 4. SwiGLU FFN
  rms_kernel<1><<<MTOK, 256, 0, stream>>>(xws, n4w, nullptr, xnb);
  gemm_bt<4><<<dim3(FF / 128, MTOK / 128), 256, 0, stream>>>(
      xnb, wg, MTOK, FF, DD, nullptr, nullptr, sg, nullptr, nullptr, nullptr);
  gemm_bt<5><<<dim3(FF / 128, MTOK / 128), 256, 0, stream>>>(
      xnb, wu, MTOK, FF, DD, nullptr, nullptr, ffin, nullptr, nullptr, sg);
  gemm_bt<0><<<dim3(DD / 128, MTOK / 128), 256, 0, stream>>>(
      ffin, wd, MTOK, DD, FF, xws, out, nullptr, nullptr, nullptr, nullptr);
}

// Round 2
// 799.687 us; speedup vs baseline: 1.1363x; 1.1363x over previous
//
#include <hip/hip_runtime.h>
#include <hip/hip_bf16.h>
#include <cstdint>

// Problem constants (setup_inputs: B=2, T=4096, D=1024, F=4096, S=4096)
#define BB   2
#define TT   4096
#define DD   1024
#define FF   4096
#define SS   4096
#define MTOK (BB * TT)   // 8192 tokens
#define NCHUNK 32
#define TCHUNK 128

typedef __bf16 bf16x8 __attribute__((ext_vector_type(8)));
typedef float  f32x4  __attribute__((ext_vector_type(4)));
typedef __attribute__((address_space(3))) char lds_char;
typedef __attribute__((address_space(1))) char g_char;

// ---------------------------------------------------------------------------
// batched fp32 -> bf16 convert for all 9 weight matrices in one dispatch
// ---------------------------------------------------------------------------
struct CvtArgs {
  const float* src[9];
  __hip_bfloat16* dst[9];
  int off4[10];  // prefix sums of float4 counts
};

__global__ __launch_bounds__(256) void cvt_all_kernel(CvtArgs a) {
  int g = blockIdx.x * 256 + threadIdx.x;
  if (g >= a.off4[9]) return;
  int s = 0;
  while (g >= a.off4[s + 1]) s++;
  int i = g - a.off4[s];
  float4 v = ((const float4*)a.src[s])[i];
  union { ushort4 u; __hip_bfloat16 h[4]; } p;
  p.h[0] = __float2bfloat16(v.x);
  p.h[1] = __float2bfloat16(v.y);
  p.h[2] = __float2bfloat16(v.z);
  p.h[3] = __float2bfloat16(v.w);
  ((ushort4*)a.dst[s])[i] = p.u;
}

// ---------------------------------------------------------------------------
// combine the 3 causal depthwise kernels into one 15-tap (padded to 16) table
// wcomb[d][j] multiplies x[t-j]; jax conv is cross-correlation so tap j uses
// w_k[d, 0, k-1-j].
// ---------------------------------------------------------------------------
__global__ void wcomb_kernel(const float* __restrict__ w3, const float* __restrict__ w7,
                             const float* __restrict__ w15, float* __restrict__ wc) {
  int d = blockIdx.x * 256 + threadIdx.x;
  if (d >= DD) return;
  for (int j = 0; j < 16; j++) {
    float v = 0.f;
    if (j < 15) {
      v = w15[d * 15 + (14 - j)];
      if (j < 7) v += w7[d * 7 + (6 - j)];
      if (j < 3) v += w3[d * 3 + (2 - j)];
    }
    wc[d * 16 + j] = v;
  }
}

// ---------------------------------------------------------------------------
// RMSNorm: one block per row of 1024, fp32 in, bf16 out
// ---------------------------------------------------------------------------
__global__ __launch_bounds__(256) void rms_kernel(const float* __restrict__ x,
                                                  const float* __restrict__ w,
                                                  __hip_bfloat16* __restrict__ ob) {
  const int row = blockIdx.x;
  const int tid = threadIdx.x;
  float4 v = ((const float4*)(x + (size_t)row * DD))[tid];
  float ss = v.x * v.x + v.y * v.y + v.z * v.z + v.w * v.w;
  for (int off = 32; off > 0; off >>= 1) ss += __shfl_down(ss, off, 64);
  __shared__ float wsum[4];
  if ((tid & 63) == 0) wsum[tid >> 6] = ss;
  __syncthreads();
  float tot = wsum[0] + wsum[1] + wsum[2] + wsum[3];
  float rinv = 1.0f / sqrtf(tot * (1.0f / DD) + 1e-6f);
  float4 wg = ((const float4*)w)[tid];
  union { ushort4 u; __hip_bfloat16 h[4]; } p;
  p.h[0] = __float2bfloat16(v.x * wg.x * rinv);
  p.h[1] = __float2bfloat16(v.y * wg.y * rinv);
  p.h[2] = __float2bfloat16(v.z * wg.z * rinv);
  p.h[3] = __float2bfloat16(v.w * wg.w * rinv);
  ((ushort4*)ob)[(size_t)row * 256 + tid] = p.u;
}

// ---------------------------------------------------------------------------
// multi-scale causal depthwise conv, 15 taps combined, LDS tiled with halo
// grid: (T/64, D/64, B), block 256. bf16 in, bf16 out, fp32 accumulate.
// ---------------------------------------------------------------------------
__global__ __launch_bounds__(256) void conv_kernel(const __hip_bfloat16* __restrict__ xn,
                                                   const float* __restrict__ wc,
                                                   __hip_bfloat16* __restrict__ outp) {
  __shared__ float xt[78][64];
  __shared__ float wt[64][15];
  const int b = blockIdx.z, t0 = blockIdx.x * 64, d0 = blockIdx.y * 64;
  const int tid = threadIdx.x;
  const int dl = tid & 63;
  for (int idx = tid; idx < 64 * 15; idx += 256) {
    int d = idx / 15, j = idx % 15;
    wt[d][j] = wc[(d0 + d) * 16 + j];
  }
  for (int r = tid >> 6; r < 78; r += 4) {
    int t = t0 - 14 + r;
    xt[r][dl] = (t >= 0) ? __bfloat162float(xn[((size_t)b * TT + t) * DD + d0 + dl]) : 0.f;
  }
  __syncthreads();
  for (int tl = tid >> 6; tl < 64; tl += 4) {
    float acc = 0.f;
#pragma unroll
    for (int j = 0; j < 15; j++) acc += wt[dl][j] * xt[tl + 14 - j][dl];
    outp[((size_t)b * TT + t0 + tl) * DD + d0 + dl] = __float2bfloat16(acc);
  }
}

// ---------------------------------------------------------------------------
// bf16 GEMM, C[M,N] = A[M,K] @ B[N,K]^T, m97 structure:
// 128x128 tile, BK=32, global_load_lds width 16, 4 waves x (4x4 of 16x16 mfma)
// XCD-aware swizzle: lin&7 (presumed XCD) owns 8 consecutive M-tiles x all N,
// so each A-tile is fetched by exactly one XCD's L2 (was: 8 XCDs each).
// Epilogues:
//  0: outf[idx] = resid[idx] + acc          (residual add, fp32)
//  1: z/htilde: bias + sigmoid on cols<1024, bf16 out (N=2048)
//  2: outb = bf16(acc)
//  4: outb = bf16(silu(acc))
//  5: outb = bf16(acc * mulin[idx])
// ---------------------------------------------------------------------------
template <int EPI>
__global__ __launch_bounds__(256, 2) void gemm_bt(
    const __hip_bfloat16* __restrict__ A, const __hip_bfloat16* __restrict__ Bm,
    const int M, const int N, const int K,
    const float* __restrict__ resid, float* __restrict__ outf,
    __hip_bfloat16* __restrict__ outb,
    const float* __restrict__ bias0, const float* __restrict__ bias1,
    const __hip_bfloat16* __restrict__ mulin) {
  __shared__ __align__(16) __hip_bfloat16 As[128 * 32];
  __shared__ __align__(16) __hip_bfloat16 Bs[128 * 32];
  const int tid = threadIdx.x;
  const int lane = tid & 63;
  const int wave = tid >> 6;
  const int fm = lane & 15, fq = lane >> 4;

  // XCD-aware swizzle (gridDim.y % 8 == 0 required; here it's always 64)
  const int nT = gridDim.x;
  const int lin = blockIdx.y * nT + blockIdx.x;
  const int xcd = lin & 7;
  const int idx_ = lin >> 3;
  const int mq = idx_ / nT;
  const int tileM = (xcd * (gridDim.y >> 3) + mq) * 128;
  const int tileN = (idx_ - mq * nT) * 128;

  const int wm = (wave & 1) * 64, wn = (wave >> 1) * 64;

  f32x4 acc[4][4] = {};

  const int srow = tid >> 2;          // 0..63
  const int scol = (tid & 3) * 8;     // bf16 element offset within BK
  const __hip_bfloat16* gA = A + (size_t)(tileM + srow) * K + scol;
  const __hip_bfloat16* gB = Bm + (size_t)(tileN + srow) * K + scol;
  lds_char* ldsA = (lds_char*)(&As[0]);
  lds_char* ldsB = (lds_char*)(&Bs[0]);
  const int wbyte = wave * 1024;      // lane*16 is implicit in global_load_lds

  for (int k0 = 0; k0 < K; k0 += 32) {
    __syncthreads();
    __builtin_amdgcn_global_load_lds((g_char*)(void*)(gA + k0),                  ldsA + wbyte,        16, 0, 0);
    __builtin_amdgcn_global_load_lds((g_char*)(void*)(gA + k0 + (size_t)64 * K), ldsA + wbyte + 4096, 16, 0, 0);
    __builtin_amdgcn_global_load_lds((g_char*)(void*)(gB + k0),                  ldsB + wbyte,        16, 0, 0);
    __builtin_amdgcn_global_load_lds((g_char*)(void*)(gB + k0 + (size_t)64 * K), ldsB + wbyte + 4096, 16, 0, 0);
    __syncthreads();
    bf16x8 af[4], bfr[4];
#pragma unroll
    for (int i = 0; i < 4; i++) {
      af[i]  = *(const bf16x8*)(As + (wm + i * 16 + fm) * 32 + fq * 8);
      bfr[i] = *(const bf16x8*)(Bs + (wn + i * 16 + fm) * 32 + fq * 8);
    }
#pragma unroll
    for (int i = 0; i < 4; i++)
#pragma unroll
      for (int j = 0; j < 4; j++)
        acc[i][j] = __builtin_amdgcn_mfma_f32_16x16x32_bf16(af[i], bfr[j], acc[i][j], 0, 0, 0);
  }

  // epilogue: C/D layout col = lane&15, row = (lane>>4)*4 + reg  [m89/m91]
#pragma unroll
  for (int i = 0; i < 4; i++) {
#pragma unroll
    for (int j = 0; j < 4; j++) {
      const int c = tileN + wn + j * 16 + fm;
#pragma unroll
      for (int r = 0; r < 4; r++) {
        const int rw = tileM + wm + i * 16 + fq * 4 + r;
        const size_t idx = (size_t)rw * N + c;
        float v = acc[i][j][r];
        if constexpr (EPI == 0) {
          outf[idx] = resid[idx] + v;
        } else if constexpr (EPI == 1) {
          v += (c < DD) ? bias0[c] : bias1[c - DD];
          if (c < DD) v = 1.f / (1.f + __expf(-v));
          outb[idx] = __float2bfloat16(v);
        } else if constexpr (EPI == 2) {
          outb[idx] = __float2bfloat16(v);
        } else if constexpr (EPI == 4) {
          outb[idx] = __float2bfloat16(v / (1.f + __expf(-v)));
        } else {
          outb[idx] = __float2bfloat16(v * __bfloat162float(mulin[idx]));
        }
      }
    }
  }
}

// ---------------------------------------------------------------------------
// MinGRU chunked parallel scan over zht [MTOK, 2048] bf16 (z | htilde)
// pass1: per-chunk affine coeffs (A,B); pass2: scan chunks; pass3: replay+add
// ---------------------------------------------------------------------------
__global__ __launch_bounds__(256) void scan_pass1(const __hip_bfloat16* __restrict__ zht,
                                                  float* __restrict__ cA,
                                                  float* __restrict__ cB) {
  const int b = blockIdx.z, c = blockIdx.y;
  const int d = blockIdx.x * 256 + threadIdx.x;
  const __hip_bfloat16* base = zht + (size_t)b * TT * 2048;
  float A = 1.f, Bc = 0.f;
  const int t0 = c * TCHUNK;
  for (int t = t0; t < t0 + TCHUNK; t++) {
    const __hip_bfloat16* rowp = base + (size_t)t * 2048;
    float z = __bfloat162float(rowp[d]);
    float h = __bfloat162float(rowp[DD + d]);
    float om = 1.f - z;
    A *= om;
    Bc = om * Bc + z * h;
  }
  size_t idx = ((size_t)b * NCHUNK + c) * DD + d;
  cA[idx] = A;
  cB[idx] = Bc;
}

__global__ __launch_bounds__(256) void scan_pass2(const float* __restrict__ hp,
                                                  const float* __restrict__ cA,
                                                  const float* __restrict__ cB,
                                                  float* __restrict__ hstart,
                                                  float* __restrict__ hlast) {
  const int b = blockIdx.y;
  const int d = blockIdx.x * 256 + threadIdx.x;
  float h = hp[b * DD + d];
  for (int c = 0; c < NCHUNK; c++) {
    size_t idx = ((size_t)b * NCHUNK + c) * DD + d;
    hstart[idx] = h;
    h = cA[idx] * h + cB[idx];
  }
  hlast[b * DD + d] = h;
}

__global__ __launch_bounds__(256) void scan_pass3(const __hip_bfloat16* __restrict__ zht,
                                                  const float* __restrict__ hstart,
                                                  float* __restrict__ x) {
  const int b = blockIdx.z, c = blockIdx.y;
  const int d = blockIdx.x * 256 + threadIdx.x;
  const __hip_bfloat16* base = zht + (size_t)b * TT * 2048;
  float h = hstart[((size_t)b * NCHUNK + c) * DD + d];
  const int t0 = c * TCHUNK;
  for (int t = t0; t < t0 + TCHUNK; t++) {
    const __hip_bfloat16* rowp = base + (size_t)t * 2048;
    float z = __bfloat162float(rowp[d]);
    float ht = __bfloat162float(rowp[DD + d]);
    h = (1.f - z) * h + z * ht;
    x[((size_t)b * TT + t) * DD + d] += h;
  }
}

// ---------------------------------------------------------------------------
// top-2 over S=4096 bf16 scores per row + softmax + gather slot_values -> bf16
// one block per row
// ---------------------------------------------------------------------------
__global__ __launch_bounds__(256) void topk_kernel(const __hip_bfloat16* __restrict__ scores,
                                                   const float* __restrict__ sv,
                                                   __hip_bfloat16* __restrict__ ret) {
  const int row = blockIdx.x;
  const int tid = threadIdx.x;
  const __hip_bfloat16* sr = scores + (size_t)row * SS;
  float v0 = -3.4e38f, v1 = -3.4e38f;
  int i0 = 0x7fffffff, i1 = 0x7fffffff;
#pragma unroll
  for (int it = 0; it < 2; it++) {
    int j0 = (it * 256 + tid) * 8;
    bf16x8 v8 = *(const bf16x8*)(sr + j0);
#pragma unroll
    for (int k = 0; k < 8; k++) {
      float v = (float)v8[k];
      int j = j0 + k;
      if (v > v0) { v1 = v0; i1 = i0; v0 = v; i0 = j; }
      else if (v > v1) { v1 = v; i1 = j; }
    }
  }
#define TKMERGE(w0, j0, w1, j1)                                              \
  {                                                                          \
    if (w0 > v0 || (w0 == v0 && j0 < i0)) {                                  \
      float t0v = v0; int t0i = i0; v0 = w0; i0 = j0;                        \
      if (t0v > w1 || (t0v == w1 && t0i < j1)) { v1 = t0v; i1 = t0i; }       \
      else { v1 = w1; i1 = j1; }                                             \
    } else {                                                                 \
      if (w0 > v1 || (w0 == v1 && j0 < i1)) { v1 = w0; i1 = j0; }            \
    }                                                                        \
  }
  for (int off = 32; off > 0; off >>= 1) {
    float w0 = __shfl_down(v0, off, 64), w1 = __shfl_down(v1, off, 64);
    int   j0 = __shfl_down(i0, off, 64), j1 = __shfl_down(i1, off, 64);
    TKMERGE(w0, j0, w1, j1);
  }
  __shared__ float wv0[4], wv1[4];
  __shared__ int   wi0[4], wi1[4];
  __shared__ float sattn[2];
  __shared__ int   sidx[2];
  if ((tid & 63) == 0) { int w = tid >> 6; wv0[w] = v0; wv1[w] = v1; wi0[w] = i0; wi1[w] = i1; }
  __syncthreads();
  if (tid == 0) {
    v0 = wv0[0]; i0 = wi0[0]; v1 = wv1[0]; i1 = wi1[0];
    for (int w = 1; w < 4; w++) { TKMERGE(wv0[w], wi0[w], wv1[w], wi1[w]); }
    float s0 = v0 * (1.f / 32.f), s1 = v1 * (1.f / 32.f);  // /sqrt(D)
    float e = __expf(s1 - s0);
    float denom = 1.f + e;
    sattn[0] = 1.f / denom;
    sattn[1] = e / denom;
    sidx[0] = i0; sidx[1] = i1;
  }
  __syncthreads();
  float a0 = sattn[0], a1 = sattn[1];
  const float4* r0 = (const float4*)(sv + (size_t)sidx[0] * DD);
  const float4* r1 = (const float4*)(sv + (size_t)sidx[1] * DD);
  float4 u = r0[tid], w4 = r1[tid];
  union { ushort4 u; __hip_bfloat16 h[4]; } p;
  p.h[0] = __float2bfloat16(a0 * u.x + a1 * w4.x);
  p.h[1] = __float2bfloat16(a0 * u.y + a1 * w4.y);
  p.h[2] = __float2bfloat16(a0 * u.z + a1 * w4.z);
  p.h[3] = __float2bfloat16(a0 * u.w + a1 * w4.w);
  ((ushort4*)(ret + (size_t)row * DD))[tid] = p.u;
#undef TKMERGE
}

// ---------------------------------------------------------------------------
extern "C" void kernel_launch(void* const* d_in, const int* in_sizes, int n_in,
                              void* d_out, int out_size, void* d_ws, size_t ws_size,
                              hipStream_t stream) {
  (void)in_sizes; (void)n_in; (void)out_size; (void)ws_size;
  const float* x_in   = (const float*)d_in[0];
  const float* h_prev = (const float*)d_in[1];
  const float* n1w    = (const float*)d_in[2];
  const float* w3     = (const float*)d_in[3];
  const float* w7     = (const float*)d_in[4];
  const float* w15    = (const float*)d_in[5];
  const float* mixw   = (const float*)d_in[6];
  const float* n2w    = (const float*)d_in[7];
  const float* wzw    = (const float*)d_in[8];
  const float* wzb    = (const float*)d_in[9];
  const float* whw    = (const float*)d_in[10];
  const float* whb    = (const float*)d_in[11];
  const float* n3w    = (const float*)d_in[12];
  const float* slotk  = (const float*)d_in[13];
  const float* slotv  = (const float*)d_in[14];
  const float* pqw    = (const float*)d_in[15];
  const float* pow_   = (const float*)d_in[16];
  const float* n4w    = (const float*)d_in[17];
  const float* gatew  = (const float*)d_in[18];
  const float* upw    = (const float*)d_in[19];
  const float* downw  = (const float*)d_in[20];
  float* out = (float*)d_out;

  char* ws = (char*)d_ws;
  size_t o = 0;
  auto alloc = [&](size_t bytes) {
    size_t r = o;
    o += (bytes + 255) & ~(size_t)255;
    return r;
  };
  __hip_bfloat16* wmix = (__hip_bfloat16*)(ws + alloc((size_t)DD * DD * 2));
  __hip_bfloat16* wzht = (__hip_bfloat16*)(ws + alloc((size_t)2 * DD * DD * 2));
  __hip_bfloat16* wpq  = (__hip_bfloat16*)(ws + alloc((size_t)DD * DD * 2));
  __hip_bfloat16* wsk  = (__hip_bfloat16*)(ws + alloc((size_t)SS * DD * 2));
  __hip_bfloat16* wpo  = (__hip_bfloat16*)(ws + alloc((size_t)DD * DD * 2));
  __hip_bfloat16* wg   = (__hip_bfloat16*)(ws + alloc((size_t)FF * DD * 2));
  __hip_bfloat16* wu   = (__hip_bfloat16*)(ws + alloc((size_t)FF * DD * 2));
  __hip_bfloat16* wd   = (__hip_bfloat16*)(ws + alloc((size_t)DD * FF * 2));
  float* wcomb = (float*)(ws + alloc((size_t)DD * 16 * 4));
  float* xws   = (float*)(ws + alloc((size_t)MTOK * DD * 4));
  __hip_bfloat16* xnb  = (__hip_bfloat16*)(ws + alloc((size_t)MTOK * DD * 2));
  __hip_bfloat16* qb   = (__hip_bfloat16*)(ws + alloc((size_t)MTOK * DD * 2));
  __hip_bfloat16* retr = (__hip_bfloat16*)(ws + alloc((size_t)MTOK * DD * 2));
  float* scanA  = (float*)(ws + alloc((size_t)BB * NCHUNK * DD * 4));
  float* scanB  = (float*)(ws + alloc((size_t)BB * NCHUNK * DD * 4));
  float* hstart = (float*)(ws + alloc((size_t)BB * NCHUNK * DD * 4));
  char* big = ws + alloc((size_t)MTOK * FF * 4);  // 134 MB shared region
  // aliases (lifetimes disjoint):
  __hip_bfloat16* xn1b  = (__hip_bfloat16*)big;                            // phase 1
  __hip_bfloat16* convb = (__hip_bfloat16*)(big + (size_t)MTOK * DD * 2);  // phase 1
  __hip_bfloat16* zhtb  = (__hip_bfloat16*)big;                            // phase 2
  __hip_bfloat16* scoresb = (__hip_bfloat16*)big;                          // phase 3
  __hip_bfloat16* sg    = (__hip_bfloat16*)big;                            // phase 4
  __hip_bfloat16* ffin  = (__hip_bfloat16*)(big + (size_t)MTOK * FF * 2);  // phase 4

  // weight conversions — one batched dispatch
  {
    CvtArgs a;
    const float* srcs[9] = {mixw, wzw, whw, pqw, slotk, pow_, gatew, upw, downw};
    __hip_bfloat16* dsts[9] = {wmix, wzht, wzht + (size_t)DD * DD, wpq, wsk, wpo, wg, wu, wd};
    int n4s[9] = {DD * DD / 4, DD * DD / 4, DD * DD / 4, DD * DD / 4, SS * DD / 4,
                  DD * DD / 4, FF * DD / 4, FF * DD / 4, DD * FF / 4};
    int acc_ = 0;
    for (int i = 0; i < 9; i++) { a.src[i] = srcs[i]; a.dst[i] = dsts[i]; a.off4[i] = acc_; acc_ += n4s[i]; }
    a.off4[9] = acc_;
    cvt_all_kernel<<<(acc_ + 255) / 256, 256, 0, stream>>>(a);
  }
  wcomb_kernel<<<DD / 256, 256, 0, stream>>>(w3, w7, w15, wcomb);

  // 1. conv block
  rms_kernel<<<MTOK, 256, 0, stream>>>(x_in, n1w, xn1b);
  conv_kernel<<<dim3(TT / 64, DD / 64, BB), 256, 0, stream>>>(xn1b, wcomb, convb);
  gemm_bt<0><<<dim3(DD / 128, MTOK / 128), 256, 0, stream>>>(
      convb, wmix, MTOK, DD, DD, x_in, xws, nullptr, nullptr, nullptr, nullptr);

  // 2. MinGRU
  rms_kernel<<<MTOK, 256, 0, stream>>>(xws, n2w, xnb);
  gemm_bt<1><<<dim3(2048 / 128, MTOK / 128), 256, 0, stream>>>(
      xnb, wzht, MTOK, 2048, DD, nullptr, nullptr, zhtb, wzb, whb, nullptr);
  scan_pass1<<<dim3(DD / 256, NCHUNK, BB), 256, 0, stream>>>(zhtb, scanA, scanB);
  scan_pass2<<<dim3(DD / 256, BB), 256, 0, stream>>>(h_prev, scanA, scanB, hstart,
                                                     out + (size_t)MTOK * DD);
  scan_pass3<<<dim3(DD / 256, NCHUNK, BB), 256, 0, stream>>>(zhtb, hstart, xws);

  // 3. slot memory
  rms_kernel<<<MTOK, 256, 0, stream>>>(xws, n3w, xnb);
  gemm_bt<2><<<dim3(DD / 128, MTOK / 128), 256, 0, stream>>>(
      xnb, wpq, MTOK, DD, DD, nullptr, nullptr, qb, nullptr, nullptr, nullptr);
  gemm_bt<2><<<dim3(SS / 128, MTOK / 128), 256, 0, stream>>>(
      qb, wsk, MTOK, SS, DD, nullptr, nullptr, scoresb, nullptr, nullptr, nullptr);
  topk_kernel<<<MTOK, 256, 0, stream>>>(scoresb, slotv, retr);
  gemm_bt<0><<<dim3(DD / 128, MTOK / 128), 256, 0, stream>>>(
      retr, wpo, MTOK, DD, DD, xws, xws, nullptr, nullptr, nullptr, nullptr);

  // 4. SwiGLU FFN
  rms_kernel<<<MTOK, 256, 0, stream>>>(xws, n4w, xnb);
  gemm_bt<4><<<dim3(FF / 128, MTOK / 128), 256, 0, stream>>>(
      xnb, wg, MTOK, FF, DD, nullptr, nullptr, sg, nullptr, nullptr, nullptr);
  gemm_bt<5><<<dim3(FF / 128, MTOK / 128), 256, 0, stream>>>(
      xnb, wu, MTOK, FF, DD, nullptr, nullptr, ffin, nullptr, nullptr, sg);
  gemm_bt<0><<<dim3(DD / 128, MTOK / 128), 256, 0, stream>>>(
      ffin, wd, MTOK, DD, FF, xws, out, nullptr, nullptr, nullptr, nullptr);
}

// Round 3
// 791.279 us; speedup vs baseline: 1.1484x; 1.0106x over previous
//
#include <hip/hip_runtime.h>
#include <hip/hip_bf16.h>
#include <cstdint>

// Problem constants (setup_inputs: B=2, T=4096, D=1024, F=4096, S=4096)
#define BB   2
#define TT   4096
#define DD   1024
#define FF   4096
#define SS   4096
#define MTOK (BB * TT)   // 8192 tokens
#define NCHUNK 32
#define TCHUNK 128

typedef __bf16 bf16x8 __attribute__((ext_vector_type(8)));
typedef float  f32x4  __attribute__((ext_vector_type(4)));
typedef __attribute__((address_space(3))) char lds_char;
typedef __attribute__((address_space(1))) char g_char;

// ---------------------------------------------------------------------------
// batched fp32 -> bf16 convert for all 9 weight matrices in one dispatch.
// mode 0: linear copy. mode 1/2: gate/up row interleave for the fused FFN
// weight: src row r (K=1024, 256 float4/row) -> dst row (r>>4)*32 + (r&15)
// (+16 for up), so a 128-col C-tile has gate cols in j-even 16-col subtiles
// and the SAME ff up cols in j-odd subtiles.
// ---------------------------------------------------------------------------
struct CvtArgs {
  const float* src[9];
  __hip_bfloat16* dst[9];
  int off4[10];  // prefix sums of float4 counts
  int mode[9];
};

__global__ __launch_bounds__(256) void cvt_all_kernel(CvtArgs a) {
  int g = blockIdx.x * 256 + threadIdx.x;
  if (g >= a.off4[9]) return;
  int s = 0;
  while (g >= a.off4[s + 1]) s++;
  int i = g - a.off4[s];
  float4 v = ((const float4*)a.src[s])[i];
  union { ushort4 u; __hip_bfloat16 h[4]; } p;
  p.h[0] = __float2bfloat16(v.x);
  p.h[1] = __float2bfloat16(v.y);
  p.h[2] = __float2bfloat16(v.z);
  p.h[3] = __float2bfloat16(v.w);
  int di = i;
  int m = a.mode[s];
  if (m) {
    int r = i >> 8, c = i & 255;
    int dr = ((r >> 4) << 5) + (r & 15) + ((m == 2) ? 16 : 0);
    di = (dr << 8) + c;
  }
  ((ushort4*)a.dst[s])[di] = p.u;
}

// ---------------------------------------------------------------------------
// combine the 3 causal depthwise kernels into one 15-tap (padded to 16) table
// ---------------------------------------------------------------------------
__global__ void wcomb_kernel(const float* __restrict__ w3, const float* __restrict__ w7,
                             const float* __restrict__ w15, float* __restrict__ wc) {
  int d = blockIdx.x * 256 + threadIdx.x;
  if (d >= DD) return;
  for (int j = 0; j < 16; j++) {
    float v = 0.f;
    if (j < 15) {
      v = w15[d * 15 + (14 - j)];
      if (j < 7) v += w7[d * 7 + (6 - j)];
      if (j < 3) v += w3[d * 3 + (2 - j)];
    }
    wc[d * 16 + j] = v;
  }
}

// ---------------------------------------------------------------------------
// RMSNorm: one block per row of 1024, fp32 in, bf16 out
// ---------------------------------------------------------------------------
__global__ __launch_bounds__(256) void rms_kernel(const float* __restrict__ x,
                                                  const float* __restrict__ w,
                                                  __hip_bfloat16* __restrict__ ob) {
  const int row = blockIdx.x;
  const int tid = threadIdx.x;
  float4 v = ((const float4*)(x + (size_t)row * DD))[tid];
  float ss = v.x * v.x + v.y * v.y + v.z * v.z + v.w * v.w;
  for (int off = 32; off > 0; off >>= 1) ss += __shfl_down(ss, off, 64);
  __shared__ float wsum[4];
  if ((tid & 63) == 0) wsum[tid >> 6] = ss;
  __syncthreads();
  float tot = wsum[0] + wsum[1] + wsum[2] + wsum[3];
  float rinv = 1.0f / sqrtf(tot * (1.0f / DD) + 1e-6f);
  float4 wg = ((const float4*)w)[tid];
  union { ushort4 u; __hip_bfloat16 h[4]; } p;
  p.h[0] = __float2bfloat16(v.x * wg.x * rinv);
  p.h[1] = __float2bfloat16(v.y * wg.y * rinv);
  p.h[2] = __float2bfloat16(v.z * wg.z * rinv);
  p.h[3] = __float2bfloat16(v.w * wg.w * rinv);
  ((ushort4*)ob)[(size_t)row * 256 + tid] = p.u;
}

// ---------------------------------------------------------------------------
// multi-scale causal depthwise conv, 15 taps combined, LDS tiled with halo
// ---------------------------------------------------------------------------
__global__ __launch_bounds__(256) void conv_kernel(const __hip_bfloat16* __restrict__ xn,
                                                   const float* __restrict__ wc,
                                                   __hip_bfloat16* __restrict__ outp) {
  __shared__ float xt[78][64];
  __shared__ float wt[64][15];
  const int b = blockIdx.z, t0 = blockIdx.x * 64, d0 = blockIdx.y * 64;
  const int tid = threadIdx.x;
  const int dl = tid & 63;
  for (int idx = tid; idx < 64 * 15; idx += 256) {
    int d = idx / 15, j = idx % 15;
    wt[d][j] = wc[(d0 + d) * 16 + j];
  }
  for (int r = tid >> 6; r < 78; r += 4) {
    int t = t0 - 14 + r;
    xt[r][dl] = (t >= 0) ? __bfloat162float(xn[((size_t)b * TT + t) * DD + d0 + dl]) : 0.f;
  }
  __syncthreads();
  for (int tl = tid >> 6; tl < 64; tl += 4) {
    float acc = 0.f;
#pragma unroll
    for (int j = 0; j < 15; j++) acc += wt[dl][j] * xt[tl + 14 - j][dl];
    outp[((size_t)b * TT + t0 + tl) * DD + d0 + dl] = __float2bfloat16(acc);
  }
}

// ---------------------------------------------------------------------------
// bf16 GEMM, C[M,N] = A[M,K] @ B[N,K]^T, m97 structure, 128x128 tile, BK=32.
// XCD-aware swizzle. Optional split-K (KSPLIT z-slices, fp32 partials).
// Epilogues:
//  1: z/htilde: bias + sigmoid on cols<1024, bf16 out (N=2048)
//  2: outb = bf16(acc)
//  6: split-K fp32 partial: outf[z*M*N + idx] = acc
//  7: fused FFN: j-even tile = gate, j-odd = up (interleaved weights);
//     outb[row*FF + ffcol] = bf16(silu(g)*u)
// ---------------------------------------------------------------------------
template <int EPI, int KSPLIT = 1>
__global__ __launch_bounds__(256, 2) void gemm_bt(
    const __hip_bfloat16* __restrict__ A, const __hip_bfloat16* __restrict__ Bm,
    const int M, const int N, const int K,
    float* __restrict__ outf, __hip_bfloat16* __restrict__ outb,
    const float* __restrict__ bias0, const float* __restrict__ bias1) {
  __shared__ __align__(16) __hip_bfloat16 As[128 * 32];
  __shared__ __align__(16) __hip_bfloat16 Bs[128 * 32];
  const int tid = threadIdx.x;
  const int lane = tid & 63;
  const int wave = tid >> 6;
  const int fm = lane & 15, fq = lane >> 4;

  // XCD-aware swizzle (gridDim.y % 8 == 0 required)
  const int nT = gridDim.x;
  const int lin = blockIdx.y * nT + blockIdx.x;
  const int xcd = lin & 7;
  const int idx_ = lin >> 3;
  const int mq = idx_ / nT;
  const int tileM = (xcd * (gridDim.y >> 3) + mq) * 128;
  const int tileN = (idx_ - mq * nT) * 128;

  const int wm = (wave & 1) * 64, wn = (wave >> 1) * 64;

  f32x4 acc[4][4] = {};

  const int srow = tid >> 2;
  const int scol = (tid & 3) * 8;
  const __hip_bfloat16* gA = A + (size_t)(tileM + srow) * K + scol;
  const __hip_bfloat16* gB = Bm + (size_t)(tileN + srow) * K + scol;
  lds_char* ldsA = (lds_char*)(&As[0]);
  lds_char* ldsB = (lds_char*)(&Bs[0]);
  const int wbyte = wave * 1024;

  const int kPer = K / KSPLIT;
  const int kBeg = (KSPLIT > 1) ? blockIdx.z * kPer : 0;
  for (int k0 = kBeg; k0 < kBeg + kPer; k0 += 32) {
    __syncthreads();
    __builtin_amdgcn_global_load_lds((g_char*)(void*)(gA + k0),                  ldsA + wbyte,        16, 0, 0);
    __builtin_amdgcn_global_load_lds((g_char*)(void*)(gA + k0 + (size_t)64 * K), ldsA + wbyte + 4096, 16, 0, 0);
    __builtin_amdgcn_global_load_lds((g_char*)(void*)(gB + k0),                  ldsB + wbyte,        16, 0, 0);
    __builtin_amdgcn_global_load_lds((g_char*)(void*)(gB + k0 + (size_t)64 * K), ldsB + wbyte + 4096, 16, 0, 0);
    __syncthreads();
    bf16x8 af[4], bfr[4];
#pragma unroll
    for (int i = 0; i < 4; i++) {
      af[i]  = *(const bf16x8*)(As + (wm + i * 16 + fm) * 32 + fq * 8);
      bfr[i] = *(const bf16x8*)(Bs + (wn + i * 16 + fm) * 32 + fq * 8);
    }
#pragma unroll
    for (int i = 0; i < 4; i++)
#pragma unroll
      for (int j = 0; j < 4; j++)
        acc[i][j] = __builtin_amdgcn_mfma_f32_16x16x32_bf16(af[i], bfr[j], acc[i][j], 0, 0, 0);
  }

  // epilogue: C/D layout col = lane&15, row = (lane>>4)*4 + reg  [m89/m91]
  if constexpr (EPI == 7) {
#pragma unroll
    for (int i = 0; i < 4; i++) {
#pragma unroll
      for (int j = 0; j < 4; j += 2) {
        const int ffcol = (((tileN + wn + j * 16) >> 5) << 4) + fm;
#pragma unroll
        for (int r = 0; r < 4; r++) {
          const int rw = tileM + wm + i * 16 + fq * 4 + r;
          float g = acc[i][j][r];
          float u = acc[i][j + 1][r];
          float v = g / (1.f + __expf(-g)) * u;
          outb[(size_t)rw * FF + ffcol] = __float2bfloat16(v);
        }
      }
    }
  } else {
#pragma unroll
    for (int i = 0; i < 4; i++) {
#pragma unroll
      for (int j = 0; j < 4; j++) {
        const int c = tileN + wn + j * 16 + fm;
#pragma unroll
        for (int r = 0; r < 4; r++) {
          const int rw = tileM + wm + i * 16 + fq * 4 + r;
          const size_t idx = (size_t)rw * N + c;
          float v = acc[i][j][r];
          if constexpr (EPI == 1) {
            v += (c < DD) ? bias0[c] : bias1[c - DD];
            if (c < DD) v = 1.f / (1.f + __expf(-v));
            outb[idx] = __float2bfloat16(v);
          } else if constexpr (EPI == 2) {
            outb[idx] = __float2bfloat16(v);
          } else if constexpr (EPI == 6) {
            outf[(size_t)blockIdx.z * M * N + idx] = v;
          }
        }
      }
    }
  }
}

// ---------------------------------------------------------------------------
// 64x128 (MxN) tile variant for grid-limited N=1024 GEMMs (mix/q/projout).
// 1024 blocks (4/CU) instead of 512. Wave tile 32x64 (2x4 mfma).
// Epilogues: 0: outf = resid + acc (fp32); 2: outb = bf16(acc)
// ---------------------------------------------------------------------------
template <int EPI>
__global__ __launch_bounds__(256, 4) void gemm_bt64(
    const __hip_bfloat16* __restrict__ A, const __hip_bfloat16* __restrict__ Bm,
    const int M, const int N, const int K,
    const float* __restrict__ resid, float* __restrict__ outf,
    __hip_bfloat16* __restrict__ outb) {
  __shared__ __align__(16) __hip_bfloat16 As[64 * 32];
  __shared__ __align__(16) __hip_bfloat16 Bs[128 * 32];
  const int tid = threadIdx.x;
  const int lane = tid & 63;
  const int wave = tid >> 6;
  const int fm = lane & 15, fq = lane >> 4;

  const int nT = gridDim.x;
  const int lin = blockIdx.y * nT + blockIdx.x;
  const int xcd = lin & 7;
  const int idx_ = lin >> 3;
  const int mq = idx_ / nT;
  const int tileM = (xcd * (gridDim.y >> 3) + mq) * 64;
  const int tileN = (idx_ - mq * nT) * 128;

  const int wm = (wave & 1) * 32, wn = (wave >> 1) * 64;

  f32x4 acc[2][4] = {};

  const int srow = tid >> 2;
  const int scol = (tid & 3) * 8;
  const __hip_bfloat16* gA = A + (size_t)(tileM + srow) * K + scol;
  const __hip_bfloat16* gB = Bm + (size_t)(tileN + srow) * K + scol;
  lds_char* ldsA = (lds_char*)(&As[0]);
  lds_char* ldsB = (lds_char*)(&Bs[0]);
  const int wbyte = wave * 1024;

  for (int k0 = 0; k0 < K; k0 += 32) {
    __syncthreads();
    __builtin_amdgcn_global_load_lds((g_char*)(void*)(gA + k0),                  ldsA + wbyte,        16, 0, 0);
    __builtin_amdgcn_global_load_lds((g_char*)(void*)(gB + k0),                  ldsB + wbyte,        16, 0, 0);
    __builtin_amdgcn_global_load_lds((g_char*)(void*)(gB + k0 + (size_t)64 * K), ldsB + wbyte + 4096, 16, 0, 0);
    __syncthreads();
    bf16x8 af[2], bfr[4];
#pragma unroll
    for (int i = 0; i < 2; i++)
      af[i]  = *(const bf16x8*)(As + (wm + i * 16 + fm) * 32 + fq * 8);
#pragma unroll
    for (int j = 0; j < 4; j++)
      bfr[j] = *(const bf16x8*)(Bs + (wn + j * 16 + fm) * 32 + fq * 8);
#pragma unroll
    for (int i = 0; i < 2; i++)
#pragma unroll
      for (int j = 0; j < 4; j++)
        acc[i][j] = __builtin_amdgcn_mfma_f32_16x16x32_bf16(af[i], bfr[j], acc[i][j], 0, 0, 0);
  }

#pragma unroll
  for (int i = 0; i < 2; i++) {
#pragma unroll
    for (int j = 0; j < 4; j++) {
      const int c = tileN + wn + j * 16 + fm;
#pragma unroll
      for (int r = 0; r < 4; r++) {
        const int rw = tileM + wm + i * 16 + fq * 4 + r;
        const size_t idx = (size_t)rw * N + c;
        float v = acc[i][j][r];
        if constexpr (EPI == 0) {
          outf[idx] = resid[idx] + v;
        } else {
          outb[idx] = __float2bfloat16(v);
        }
      }
    }
  }
}

// ---------------------------------------------------------------------------
// split-K fixup for the down projection: out = resid + P0 + P1
// ---------------------------------------------------------------------------
__global__ __launch_bounds__(256) void reduce_down(const float* __restrict__ P,
                                                   const float* __restrict__ resid,
                                                   float* __restrict__ out) {
  size_t i = (size_t)blockIdx.x * 256 + threadIdx.x;
  float4 a = ((const float4*)P)[i];
  float4 b = ((const float4*)(P + (size_t)MTOK * DD))[i];
  float4 rr = ((const float4*)resid)[i];
  float4 o;
  o.x = rr.x + a.x + b.x; o.y = rr.y + a.y + b.y;
  o.z = rr.z + a.z + b.z; o.w = rr.w + a.w + b.w;
  ((float4*)out)[i] = o;
}

// ---------------------------------------------------------------------------
// MinGRU chunked parallel scan over zht [MTOK, 2048] bf16 (z | htilde)
// ---------------------------------------------------------------------------
__global__ __launch_bounds__(256) void scan_pass1(const __hip_bfloat16* __restrict__ zht,
                                                  float* __restrict__ cA,
                                                  float* __restrict__ cB) {
  const int b = blockIdx.z, c = blockIdx.y;
  const int d = blockIdx.x * 256 + threadIdx.x;
  const __hip_bfloat16* base = zht + (size_t)b * TT * 2048;
  float A = 1.f, Bc = 0.f;
  const int t0 = c * TCHUNK;
  for (int t = t0; t < t0 + TCHUNK; t++) {
    const __hip_bfloat16* rowp = base + (size_t)t * 2048;
    float z = __bfloat162float(rowp[d]);
    float h = __bfloat162float(rowp[DD + d]);
    float om = 1.f - z;
    A *= om;
    Bc = om * Bc + z * h;
  }
  size_t idx = ((size_t)b * NCHUNK + c) * DD + d;
  cA[idx] = A;
  cB[idx] = Bc;
}

__global__ __launch_bounds__(256) void scan_pass2(const float* __restrict__ hp,
                                                  const float* __restrict__ cA,
                                                  const float* __restrict__ cB,
                                                  float* __restrict__ hstart,
                                                  float* __restrict__ hlast) {
  const int b = blockIdx.y;
  const int d = blockIdx.x * 256 + threadIdx.x;
  float h = hp[b * DD + d];
  for (int c = 0; c < NCHUNK; c++) {
    size_t idx = ((size_t)b * NCHUNK + c) * DD + d;
    hstart[idx] = h;
    h = cA[idx] * h + cB[idx];
  }
  hlast[b * DD + d] = h;
}

__global__ __launch_bounds__(256) void scan_pass3(const __hip_bfloat16* __restrict__ zht,
                                                  const float* __restrict__ hstart,
                                                  float* __restrict__ x) {
  const int b = blockIdx.z, c = blockIdx.y;
  const int d = blockIdx.x * 256 + threadIdx.x;
  const __hip_bfloat16* base = zht + (size_t)b * TT * 2048;
  float h = hstart[((size_t)b * NCHUNK + c) * DD + d];
  const int t0 = c * TCHUNK;
  for (int t = t0; t < t0 + TCHUNK; t++) {
    const __hip_bfloat16* rowp = base + (size_t)t * 2048;
    float z = __bfloat162float(rowp[d]);
    float ht = __bfloat162float(rowp[DD + d]);
    h = (1.f - z) * h + z * ht;
    x[((size_t)b * TT + t) * DD + d] += h;
  }
}

// ---------------------------------------------------------------------------
// top-2 over S=4096 bf16 scores per row + softmax + gather slot_values -> bf16
// ---------------------------------------------------------------------------
__global__ __launch_bounds__(256) void topk_kernel(const __hip_bfloat16* __restrict__ scores,
                                                   const float* __restrict__ sv,
                                                   __hip_bfloat16* __restrict__ ret) {
  const int row = blockIdx.x;
  const int tid = threadIdx.x;
  const __hip_bfloat16* sr = scores + (size_t)row * SS;
  float v0 = -3.4e38f, v1 = -3.4e38f;
  int i0 = 0x7fffffff, i1 = 0x7fffffff;
#pragma unroll
  for (int it = 0; it < 2; it++) {
    int j0 = (it * 256 + tid) * 8;
    bf16x8 v8 = *(const bf16x8*)(sr + j0);
#pragma unroll
    for (int k = 0; k < 8; k++) {
      float v = (float)v8[k];
      int j = j0 + k;
      if (v > v0) { v1 = v0; i1 = i0; v0 = v; i0 = j; }
      else if (v > v1) { v1 = v; i1 = j; }
    }
  }
#define TKMERGE(w0, j0, w1, j1)                                              \
  {                                                                          \
    if (w0 > v0 || (w0 == v0 && j0 < i0)) {                                  \
      float t0v = v0; int t0i = i0; v0 = w0; i0 = j0;                        \
      if (t0v > w1 || (t0v == w1 && t0i < j1)) { v1 = t0v; i1 = t0i; }       \
      else { v1 = w1; i1 = j1; }                                             \
    } else {                                                                 \
      if (w0 > v1 || (w0 == v1 && j0 < i1)) { v1 = w0; i1 = j0; }            \
    }                                                                        \
  }
  for (int off = 32; off > 0; off >>= 1) {
    float w0 = __shfl_down(v0, off, 64), w1 = __shfl_down(v1, off, 64);
    int   j0 = __shfl_down(i0, off, 64), j1 = __shfl_down(i1, off, 64);
    TKMERGE(w0, j0, w1, j1);
  }
  __shared__ float wv0[4], wv1[4];
  __shared__ int   wi0[4], wi1[4];
  __shared__ float sattn[2];
  __shared__ int   sidx[2];
  if ((tid & 63) == 0) { int w = tid >> 6; wv0[w] = v0; wv1[w] = v1; wi0[w] = i0; wi1[w] = i1; }
  __syncthreads();
  if (tid == 0) {
    v0 = wv0[0]; i0 = wi0[0]; v1 = wv1[0]; i1 = wi1[0];
    for (int w = 1; w < 4; w++) { TKMERGE(wv0[w], wi0[w], wv1[w], wi1[w]); }
    float s0 = v0 * (1.f / 32.f), s1 = v1 * (1.f / 32.f);  // /sqrt(D)
    float e = __expf(s1 - s0);
    float denom = 1.f + e;
    sattn[0] = 1.f / denom;
    sattn[1] = e / denom;
    sidx[0] = i0; sidx[1] = i1;
  }
  __syncthreads();
  float a0 = sattn[0], a1 = sattn[1];
  const float4* r0 = (const float4*)(sv + (size_t)sidx[0] * DD);
  const float4* r1 = (const float4*)(sv + (size_t)sidx[1] * DD);
  float4 u = r0[tid], w4 = r1[tid];
  union { ushort4 u; __hip_bfloat16 h[4]; } p;
  p.h[0] = __float2bfloat16(a0 * u.x + a1 * w4.x);
  p.h[1] = __float2bfloat16(a0 * u.y + a1 * w4.y);
  p.h[2] = __float2bfloat16(a0 * u.z + a1 * w4.z);
  p.h[3] = __float2bfloat16(a0 * u.w + a1 * w4.w);
  ((ushort4*)(ret + (size_t)row * DD))[tid] = p.u;
#undef TKMERGE
}

// ---------------------------------------------------------------------------
extern "C" void kernel_launch(void* const* d_in, const int* in_sizes, int n_in,
                              void* d_out, int out_size, void* d_ws, size_t ws_size,
                              hipStream_t stream) {
  (void)in_sizes; (void)n_in; (void)out_size; (void)ws_size;
  const float* x_in   = (const float*)d_in[0];
  const float* h_prev = (const float*)d_in[1];
  const float* n1w    = (const float*)d_in[2];
  const float* w3     = (const float*)d_in[3];
  const float* w7     = (const float*)d_in[4];
  const float* w15    = (const float*)d_in[5];
  const float* mixw   = (const float*)d_in[6];
  const float* n2w    = (const float*)d_in[7];
  const float* wzw    = (const float*)d_in[8];
  const float* wzb    = (const float*)d_in[9];
  const float* whw    = (const float*)d_in[10];
  const float* whb    = (const float*)d_in[11];
  const float* n3w    = (const float*)d_in[12];
  const float* slotk  = (const float*)d_in[13];
  const float* slotv  = (const float*)d_in[14];
  const float* pqw    = (const float*)d_in[15];
  const float* pow_   = (const float*)d_in[16];
  const float* n4w    = (const float*)d_in[17];
  const float* gatew  = (const float*)d_in[18];
  const float* upw    = (const float*)d_in[19];
  const float* downw  = (const float*)d_in[20];
  float* out = (float*)d_out;

  char* ws = (char*)d_ws;
  size_t o = 0;
  auto alloc = [&](size_t bytes) {
    size_t r = o;
    o += (bytes + 255) & ~(size_t)255;
    return r;
  };
  __hip_bfloat16* wmix = (__hip_bfloat16*)(ws + alloc((size_t)DD * DD * 2));
  __hip_bfloat16* wzht = (__hip_bfloat16*)(ws + alloc((size_t)2 * DD * DD * 2));
  __hip_bfloat16* wpq  = (__hip_bfloat16*)(ws + alloc((size_t)DD * DD * 2));
  __hip_bfloat16* wsk  = (__hip_bfloat16*)(ws + alloc((size_t)SS * DD * 2));
  __hip_bfloat16* wpo  = (__hip_bfloat16*)(ws + alloc((size_t)DD * DD * 2));
  __hip_bfloat16* wfu  = (__hip_bfloat16*)(ws + alloc((size_t)2 * FF * DD * 2));  // gate/up interleaved
  __hip_bfloat16* wd   = (__hip_bfloat16*)(ws + alloc((size_t)DD * FF * 2));
  float* wcomb = (float*)(ws + alloc((size_t)DD * 16 * 4));
  float* xws   = (float*)(ws + alloc((size_t)MTOK * DD * 4));
  __hip_bfloat16* xnb  = (__hip_bfloat16*)(ws + alloc((size_t)MTOK * DD * 2));
  __hip_bfloat16* qb   = (__hip_bfloat16*)(ws + alloc((size_t)MTOK * DD * 2));
  __hip_bfloat16* retr = (__hip_bfloat16*)(ws + alloc((size_t)MTOK * DD * 2));
  float* scanA  = (float*)(ws + alloc((size_t)BB * NCHUNK * DD * 4));
  float* scanB  = (float*)(ws + alloc((size_t)BB * NCHUNK * DD * 4));
  float* hstart = (float*)(ws + alloc((size_t)BB * NCHUNK * DD * 4));
  char* big = ws + alloc((size_t)MTOK * FF * 4);  // 134 MB shared region
  // aliases (lifetimes disjoint):
  __hip_bfloat16* xn1b  = (__hip_bfloat16*)big;                            // phase 1
  __hip_bfloat16* convb = (__hip_bfloat16*)(big + (size_t)MTOK * DD * 2);  // phase 1
  __hip_bfloat16* zhtb  = (__hip_bfloat16*)big;                            // phase 2
  __hip_bfloat16* scoresb = (__hip_bfloat16*)big;                          // phase 3
  __hip_bfloat16* ffin  = (__hip_bfloat16*)big;                            // phase 4
  float* Pbuf           = (float*)(big + (size_t)MTOK * FF * 2);           // phase 4 (2x33.5MB)

  // weight conversions — one batched dispatch (gate/up row-interleaved)
  {
    CvtArgs a;
    const float* srcs[9] = {mixw, wzw, whw, pqw, slotk, pow_, gatew, upw, downw};
    __hip_bfloat16* dsts[9] = {wmix, wzht, wzht + (size_t)DD * DD, wpq, wsk, wpo, wfu, wfu, wd};
    int n4s[9] = {DD * DD / 4, DD * DD / 4, DD * DD / 4, DD * DD / 4, SS * DD / 4,
                  DD * DD / 4, FF * DD / 4, FF * DD / 4, DD * FF / 4};
    int modes[9] = {0, 0, 0, 0, 0, 0, 1, 2, 0};
    int acc_ = 0;
    for (int i = 0; i < 9; i++) {
      a.src[i] = srcs[i]; a.dst[i] = dsts[i]; a.off4[i] = acc_; a.mode[i] = modes[i];
      acc_ += n4s[i];
    }
    a.off4[9] = acc_;
    cvt_all_kernel<<<(acc_ + 255) / 256, 256, 0, stream>>>(a);
  }
  wcomb_kernel<<<DD / 256, 256, 0, stream>>>(w3, w7, w15, wcomb);

  // 1. conv block
  rms_kernel<<<MTOK, 256, 0, stream>>>(x_in, n1w, xn1b);
  conv_kernel<<<dim3(TT / 64, DD / 64, BB), 256, 0, stream>>>(xn1b, wcomb, convb);
  gemm_bt64<0><<<dim3(DD / 128, MTOK / 64), 256, 0, stream>>>(
      convb, wmix, MTOK, DD, DD, x_in, xws, nullptr);

  // 2. MinGRU
  rms_kernel<<<MTOK, 256, 0, stream>>>(xws, n2w, xnb);
  gemm_bt<1><<<dim3(2048 / 128, MTOK / 128), 256, 0, stream>>>(
      xnb, wzht, MTOK, 2048, DD, nullptr, zhtb, wzb, whb);
  scan_pass1<<<dim3(DD / 256, NCHUNK, BB), 256, 0, stream>>>(zhtb, scanA, scanB);
  scan_pass2<<<dim3(DD / 256, BB), 256, 0, stream>>>(h_prev, scanA, scanB, hstart,
                                                     out + (size_t)MTOK * DD);
  scan_pass3<<<dim3(DD / 256, NCHUNK, BB), 256, 0, stream>>>(zhtb, hstart, xws);

  // 3. slot memory
  rms_kernel<<<MTOK, 256, 0, stream>>>(xws, n3w, xnb);
  gemm_bt64<2><<<dim3(DD / 128, MTOK / 64), 256, 0, stream>>>(
      xnb, wpq, MTOK, DD, DD, nullptr, nullptr, qb);
  gemm_bt<2><<<dim3(SS / 128, MTOK / 128), 256, 0, stream>>>(
      qb, wsk, MTOK, SS, DD, nullptr, scoresb, nullptr, nullptr);
  topk_kernel<<<MTOK, 256, 0, stream>>>(scoresb, slotv, retr);
  gemm_bt64<0><<<dim3(DD / 128, MTOK / 64), 256, 0, stream>>>(
      retr, wpo, MTOK, DD, DD, xws, xws, nullptr);

  // 4. SwiGLU FFN (fused gate+up, then split-K down + reduce)
  rms_kernel<<<MTOK, 256, 0, stream>>>(xws, n4w, xnb);
  gemm_bt<7><<<dim3(2 * FF / 128, MTOK / 128), 256, 0, stream>>>(
      xnb, wfu, MTOK, 2 * FF, DD, nullptr, ffin, nullptr, nullptr);
  gemm_bt<6, 2><<<dim3(DD / 128, MTOK / 128, 2), 256, 0, stream>>>(
      ffin, wd, MTOK, DD, FF, Pbuf, nullptr, nullptr, nullptr);
  reduce_down<<<MTOK * DD / 1024, 256, 0, stream>>>(Pbuf, xws, out);
}